// Round 3
// baseline (57.741 us; speedup 1.0000x reference)
//
#include <hip/hip_runtime.h>

// EKV nonlinear conv2d, MI355X.
// out[b,co,h,w] = alpha * sum_{cin,i,j} sp((v-th)*inv)^2 - sp((v-th-0.1)*inv)^2
// log2-domain: e1 = 2^(v*s) * 2^(-th*s), e2 = e1*KF,
//   term = ln2^2 * (log2(1+e1)^2 - log2(1+e2)^2)
//
// v4 changes vs 42.6us v3 (which was latency/imbalance-bound: VALUBusy 39%,
// Occupancy 11% of a 25% cap — only 2 blocks/CU, data-dependent tails):
//  - 4x wave parallelism at constant work: block = (b, co, window); its 4
//    waves all cover the SAME 8-row window and split the active-cin mask
//    4 ways by set-bit rank (balanced). Grid 2048 -> 8 blocks/CU ->
//    32 waves/CU (100% theoretical occupancy; was 25%).
//  - Partials combined through 4KB LDS + one end barrier (no atomics).
//  - Main loop still barrier-free, per-wave private LDS window buffers,
//    depth-1 software pipeline on global loads.

constexpr int CIN  = 64;
constexpr int COUT = 128;
constexpr int HW   = 32;
constexpr int PIX  = HW * HW;       // 1024
constexpr int LROW = 40;            // wave-buffer row stride (160B, keeps 16B align)

constexpr float S     = 19.235933878519512f;     // (1/0.075) * log2(e)
constexpr float KF    = 0.26359713811572677f;    // exp(-0.1/0.075)
constexpr float OSC   = 2.7025482032899376e-4f;  // alpha * ln2^2
constexpr float DELTA = 0.5718460f;              // 11/S: skip => per-term < 2^-22

// ---- pre-kernel: wg[(b*CIN+cin)*4 + w] = max V over rows 8w-1..8w+8 (0 incl. halo)
__global__ __launch_bounds__(256)
void ekv_rowmax(const float* __restrict__ V, float* __restrict__ wg)
{
    const int t = threadIdx.x;
    const int plane = blockIdx.x;               // b*CIN + cin
    __shared__ float rmax[32];
    const float4 v4 = reinterpret_cast<const float4*>(V + (size_t)plane * PIX)[t];
    float m = fmaxf(fmaxf(v4.x, v4.y), fmaxf(v4.z, v4.w));
    m = fmaxf(m, __shfl_xor(m, 1));             // reduce 8 lanes of one row
    m = fmaxf(m, __shfl_xor(m, 2));
    m = fmaxf(m, __shfl_xor(m, 4));
    if ((t & 7) == 0) rmax[t >> 3] = m;
    __syncthreads();
    if (t < 4) {
        float wm = 0.0f;                        // halo pixels are v=0 -> e=1
        #pragma unroll
        for (int rr = 0; rr < 10; ++rr) {
            const int r = 8 * t - 1 + rr;
            if (r >= 0 && r < 32) wm = fmaxf(wm, rmax[r]);
        }
        wg[plane * 4 + t] = wm;
    }
}

// ---- main kernel: block = (b, co, window); 4 waves split cin by rank mod 4
__global__ __launch_bounds__(256, 8)
void ekv_main(const float* __restrict__ V, const float* __restrict__ Th,
              const float* __restrict__ wg, float* __restrict__ Out)
{
    const int t     = threadIdx.x;
    const int win   = blockIdx.x & 3;                 // 8-row window 0..3
    const int co    = (blockIdx.x >> 2) & (COUT - 1);
    const int b     = blockIdx.x >> 9;
    const int phase = t >> 6;                         // cin split 0..3
    const int lane  = t & 63;

    __shared__ float  Ew[4][10 * LROW];   // per-wave private window buffers
    __shared__ float  Qs[CIN * 9];        // exp2(-theta*S), block-shared
    __shared__ float4 Cb[256];            // cross-phase combine buffer

    const float* vbase = V  + (size_t)b  * CIN * PIX;
    const float* thp   = Th + (size_t)co * (CIN * 9);

    for (int i = t; i < CIN * 9; i += 256)
        Qs[i] = __builtin_amdgcn_exp2f(-thp[i] * S);

    // lane l tests cin=l: active iff window vmax >= min_k(theta)-DELTA
    float thmin = 1e30f;
    #pragma unroll
    for (int k = 0; k < 9; ++k) thmin = fminf(thmin, thp[lane * 9 + k]);
    const float wgv = wg[(size_t)(b * CIN + lane) * 4 + win];
    unsigned long long full = __ballot(wgv >= thmin - DELTA);

    // rank-interleaved 4-way split of the active set (balanced across phases)
    unsigned long long mask = 0;
    {
        unsigned long long m = full; int idx = 0;
        while (m) {
            const int c = (int)__builtin_ctzll(m); m &= m - 1;
            if ((idx & 3) == phase) mask |= 1ull << c;
            ++idx;
        }
    }

    // one-time halo init of this wave's buffer (never overwritten after)
    float* EB = Ew[phase];
    if (lane < 10) { EB[lane * LROW] = 1.0f; EB[lane * LROW + 33] = 1.0f; }
    if (win == 0 && lane < 34) EB[lane] = 1.0f;               // global row -1
    if (win == 3 && lane < 34) EB[9 * LROW + lane] = 1.0f;    // global row 32

    __syncthreads();    // Qs ready

    const int lr = lane >> 3;                   // 0..7
    const int lc = (lane & 7) * 4;              // 0..28
    // primary load -> buffer row 1+lr (global row 8win+lr, always in range)
    // secondary: lanes 0..7 -> buffer row 0 (8win-1), 8..15 -> row 9 (8win+8)
    const bool sec  = (lane < 8) ? (win != 0) : ((lane < 16) ? (win != 3) : false);
    const int  srow = (lane < 8) ? 0 : 9;
    const int  sgr  = 8 * win - 1 + srow;

    float acc0 = 0.f, acc1 = 0.f, acc2 = 0.f, acc3 = 0.f;

    if (mask) {
        int cin = (int)__builtin_ctzll(mask); mask &= mask - 1;
        const float* src = vbase + cin * PIX;
        float4 pa = *reinterpret_cast<const float4*>(src + (8 * win + lr) * HW + lc);
        float4 pb = make_float4(0.f, 0.f, 0.f, 0.f);
        if (sec) pb = *reinterpret_cast<const float4*>(src + sgr * HW + lc);

        for (;;) {
            int nxt = -1;
            if (mask) { nxt = (int)__builtin_ctzll(mask); mask &= mask - 1; }

            // stage current plane into the wave buffer (waits vmcnt on pa/pb)
            {
                float* d = &EB[(1 + lr) * LROW + 1 + lc];
                d[0] = __builtin_amdgcn_exp2f(pa.x * S);
                d[1] = __builtin_amdgcn_exp2f(pa.y * S);
                d[2] = __builtin_amdgcn_exp2f(pa.z * S);
                d[3] = __builtin_amdgcn_exp2f(pa.w * S);
                if (sec) {
                    float* d2 = &EB[srow * LROW + 1 + lc];
                    d2[0] = __builtin_amdgcn_exp2f(pb.x * S);
                    d2[1] = __builtin_amdgcn_exp2f(pb.y * S);
                    d2[2] = __builtin_amdgcn_exp2f(pb.z * S);
                    d2[3] = __builtin_amdgcn_exp2f(pb.w * S);
                }
            }

            // issue next plane's loads now; latency hides under compute below
            float4 na = pa, nb = pb;
            if (nxt >= 0) {
                const float* s2 = vbase + nxt * PIX;
                na = *reinterpret_cast<const float4*>(s2 + (8 * win + lr) * HW + lc);
                if (sec) nb = *reinterpret_cast<const float4*>(s2 + sgr * HW + lc);
            }

            // compute current plane from the wave buffer
            {
                float q1[9], q2[9];
                #pragma unroll
                for (int k = 0; k < 9; ++k) {
                    q1[k] = Qs[cin * 9 + k];    // broadcast reads
                    q2[k] = q1[k] * KF;
                }
                #pragma unroll
                for (int i = 0; i < 3; ++i) {
                    const float* rowp = &EB[(lr + i) * LROW + lc];   // 16B aligned
                    const float4 m4 = *reinterpret_cast<const float4*>(rowp);
                    const float2 n2 = *reinterpret_cast<const float2*>(rowp + 4);
                    const float vals[6] = {m4.x, m4.y, m4.z, m4.w, n2.x, n2.y};
                    #pragma unroll
                    for (int j = 0; j < 3; ++j) {
                        const float qa = q1[i * 3 + j];
                        const float qb = q2[i * 3 + j];
                        #pragma unroll
                        for (int k = 0; k < 4; ++k) {
                            const float x1 = __builtin_fmaf(vals[k + j], qa, 1.0f);
                            const float x2 = __builtin_fmaf(vals[k + j], qb, 1.0f);
                            const float l1 = __builtin_amdgcn_logf(x1);   // log2
                            const float l2 = __builtin_amdgcn_logf(x2);
                            const float su = l1 + l2, di = l1 - l2;       // l1^2-l2^2
                            if      (k == 0) acc0 = __builtin_fmaf(su, di, acc0);
                            else if (k == 1) acc1 = __builtin_fmaf(su, di, acc1);
                            else if (k == 2) acc2 = __builtin_fmaf(su, di, acc2);
                            else             acc3 = __builtin_fmaf(su, di, acc3);
                        }
                    }
                }
            }

            if (nxt < 0) break;
            pa = na; pb = nb; cin = nxt;
        }
    }

    // cross-phase combine: 4 partials per pixel group -> one float4 store
    Cb[t] = make_float4(acc0, acc1, acc2, acc3);
    __syncthreads();
    if (t < 64) {
        const float4 p0 = Cb[t];
        const float4 p1 = Cb[t + 64];
        const float4 p2 = Cb[t + 128];
        const float4 p3 = Cb[t + 192];
        float4 o;
        o.x = (p0.x + p1.x + p2.x + p3.x) * OSC;
        o.y = (p0.y + p1.y + p2.y + p3.y) * OSC;
        o.z = (p0.z + p1.z + p2.z + p3.z) * OSC;
        o.w = (p0.w + p1.w + p2.w + p3.w) * OSC;
        // window px (t>>3, (t&7)*4 ..+3) = flat win*256 + 4t
        float* obase = Out + (size_t)(b * COUT + co) * PIX + win * 256;
        reinterpret_cast<float4*>(obase)[t] = o;
    }
}

extern "C" void kernel_launch(void* const* d_in, const int* in_sizes, int n_in,
                              void* d_out, int out_size, void* d_ws, size_t ws_size,
                              hipStream_t stream) {
    (void)in_sizes; (void)n_in; (void)ws_size; (void)out_size;
    const float* V  = (const float*)d_in[0];   // (4,64,32,32)
    const float* Th = (const float*)d_in[1];   // (128,64,3,3)
    float* Out = (float*)d_out;                // (4,128,32,32)
    float* wg  = (float*)d_ws;                 // 4*64*4 floats = 4 KB
    ekv_rowmax<<<dim3(4 * CIN), dim3(256), 0, stream>>>(V, wg);
    ekv_main<<<dim3(4 * COUT * 4), dim3(256), 0, stream>>>(V, Th, wg, Out);
}

// Round 4
// 50.066 us; speedup vs baseline: 1.1533x; 1.1533x over previous
//
#include <hip/hip_runtime.h>

// EKV nonlinear conv2d, MI355X.
// out[b,co,h,w] = alpha * sum_{cin,i,j} sp((v-th)*inv)^2 - sp((v-th-0.1)*inv)^2
// log2-domain: e1 = 2^(v*s) * 2^(-th*s), e2 = e1*KF,
//   term = ln2^2 * (log2(1+e1)^2 - log2(1+e2)^2)
//
// v5 changes vs 57.7us v4 (regression post-mortem: FETCH 3.2->32MB, i.e. the
// all-resident 2048-block grid scattered (b,co)-sharing tasks across XCDs and
// destroyed L2 locality; stalls grew despite 4x occupancy):
//  - XCD-aware bijective swizzle: task=(h&7)*256+(h>>3). Each XCD owns a
//    contiguous 256-task chunk (one b, 64 co) -> working set 0.4MB << 4MB L2.
//  - Depth-2 software pipeline (ping-pong A/B register sets, loads issued two
//    planes ahead): ~1400cy latency budget, covers L3 on residual misses.
//  - O(1) rank split via popcll+ballot (was a 64-iter serial loop).
// Kept from v4: block=(b,co,window), 4 waves rank-split the active-cin mask,
// zero main-loop barriers, per-wave private LDS buffers, LDS combine.

constexpr int CIN  = 64;
constexpr int COUT = 128;
constexpr int HW   = 32;
constexpr int PIX  = HW * HW;       // 1024
constexpr int LROW = 40;            // wave-buffer row stride (160B, keeps 16B align)

constexpr float S     = 19.235933878519512f;     // (1/0.075) * log2(e)
constexpr float KF    = 0.26359713811572677f;    // exp(-0.1/0.075)
constexpr float OSC   = 2.7025482032899376e-4f;  // alpha * ln2^2
constexpr float DELTA = 0.5718460f;              // 11/S: skip => per-term < 2^-22

// ---- pre-kernel: wg[(b*CIN+cin)*4 + w] = max V over rows 8w-1..8w+8 (0 incl. halo)
__global__ __launch_bounds__(256)
void ekv_rowmax(const float* __restrict__ V, float* __restrict__ wg)
{
    const int t = threadIdx.x;
    const int plane = blockIdx.x;               // b*CIN + cin
    __shared__ float rmax[32];
    const float4 v4 = reinterpret_cast<const float4*>(V + (size_t)plane * PIX)[t];
    float m = fmaxf(fmaxf(v4.x, v4.y), fmaxf(v4.z, v4.w));
    m = fmaxf(m, __shfl_xor(m, 1));             // reduce 8 lanes of one row
    m = fmaxf(m, __shfl_xor(m, 2));
    m = fmaxf(m, __shfl_xor(m, 4));
    if ((t & 7) == 0) rmax[t >> 3] = m;
    __syncthreads();
    if (t < 4) {
        float wm = 0.0f;                        // halo pixels are v=0 -> e=1
        #pragma unroll
        for (int rr = 0; rr < 10; ++rr) {
            const int r = 8 * t - 1 + rr;
            if (r >= 0 && r < 32) wm = fmaxf(wm, rmax[r]);
        }
        wg[plane * 4 + t] = wm;
    }
}

// ---- main kernel: task = (b, co, window); 4 waves split cin by set-bit rank
__global__ __launch_bounds__(256, 8)
void ekv_main(const float* __restrict__ V, const float* __restrict__ Th,
              const float* __restrict__ wg, float* __restrict__ Out)
{
    const int t = threadIdx.x;
    // XCD-aware bijective swizzle (nwg=2048, 8 XCDs): XCD x gets a contiguous
    // 256-task chunk = one b, 64 consecutive co -> L2-resident working set.
    const int task  = ((blockIdx.x & 7) << 8) | (blockIdx.x >> 3);
    const int win   = task & 3;                       // 8-row window 0..3
    const int co    = (task >> 2) & (COUT - 1);
    const int b     = task >> 9;
    const int phase = t >> 6;                         // cin split 0..3
    const int lane  = t & 63;

    __shared__ float  Ew[4][10 * LROW];   // per-wave private window buffers
    __shared__ float  Qs[CIN * 9];        // exp2(-theta*S), block-shared
    __shared__ float4 Cb[256];            // cross-phase combine buffer

    const float* vbase = V  + (size_t)b  * CIN * PIX;
    const float* thp   = Th + (size_t)co * (CIN * 9);

    for (int i = t; i < CIN * 9; i += 256)
        Qs[i] = __builtin_amdgcn_exp2f(-thp[i] * S);

    // lane l tests cin=l: active iff window vmax >= min_k(theta)-DELTA
    float thmin = 1e30f;
    #pragma unroll
    for (int k = 0; k < 9; ++k) thmin = fminf(thmin, thp[lane * 9 + k]);
    const float wgv = wg[(size_t)(b * CIN + lane) * 4 + win];
    const unsigned long long full = __ballot(wgv >= thmin - DELTA);

    // rank-interleaved 4-way split of the active set (balanced across phases)
    const bool actv = (full >> lane) & 1ull;
    const int  rank = (int)__popcll(full & ((1ull << lane) - 1ull));
    unsigned long long mask = __ballot(actv && ((rank & 3) == phase));

    // one-time halo init of this wave's buffer (never overwritten after)
    float* EB = Ew[phase];
    if (lane < 10) { EB[lane * LROW] = 1.0f; EB[lane * LROW + 33] = 1.0f; }
    if (win == 0 && lane < 34) EB[lane] = 1.0f;               // global row -1
    if (win == 3 && lane < 34) EB[9 * LROW + lane] = 1.0f;    // global row 32

    __syncthreads();    // Qs ready

    const int lr = lane >> 3;                   // 0..7
    const int lc = (lane & 7) * 4;              // 0..28
    // primary load -> buffer row 1+lr (global row 8win+lr, always in range)
    // secondary: lanes 0..7 -> buffer row 0 (8win-1), 8..15 -> row 9 (8win+8)
    const bool sec  = (lane < 8) ? (win != 0) : ((lane < 16) ? (win != 3) : false);
    const int  srow = (lane < 8) ? 0 : 9;
    const int  sgr  = 8 * win - 1 + srow;

    float acc0 = 0.f, acc1 = 0.f, acc2 = 0.f, acc3 = 0.f;

    auto pop = [&]() -> int {
        if (!mask) return -1;
        const int c = (int)__builtin_ctzll(mask); mask &= mask - 1; return c;
    };
    auto issue = [&](int cin, float4& a, float4& bb) {
        const float* src = vbase + cin * PIX;
        a = *reinterpret_cast<const float4*>(src + (8 * win + lr) * HW + lc);
        if (sec) bb = *reinterpret_cast<const float4*>(src + sgr * HW + lc);
    };
    auto stage = [&](const float4& a, const float4& bb) {
        float* d = &EB[(1 + lr) * LROW + 1 + lc];
        d[0] = __builtin_amdgcn_exp2f(a.x * S);
        d[1] = __builtin_amdgcn_exp2f(a.y * S);
        d[2] = __builtin_amdgcn_exp2f(a.z * S);
        d[3] = __builtin_amdgcn_exp2f(a.w * S);
        if (sec) {
            float* d2 = &EB[srow * LROW + 1 + lc];
            d2[0] = __builtin_amdgcn_exp2f(bb.x * S);
            d2[1] = __builtin_amdgcn_exp2f(bb.y * S);
            d2[2] = __builtin_amdgcn_exp2f(bb.z * S);
            d2[3] = __builtin_amdgcn_exp2f(bb.w * S);
        }
    };
    auto compute = [&](int cin) {
        float q1[9], q2[9];
        #pragma unroll
        for (int k = 0; k < 9; ++k) {
            q1[k] = Qs[cin * 9 + k];    // broadcast reads
            q2[k] = q1[k] * KF;
        }
        #pragma unroll
        for (int i = 0; i < 3; ++i) {
            const float* rowp = &EB[(lr + i) * LROW + lc];   // 16B aligned
            const float4 m4 = *reinterpret_cast<const float4*>(rowp);
            const float2 n2 = *reinterpret_cast<const float2*>(rowp + 4);
            const float vals[6] = {m4.x, m4.y, m4.z, m4.w, n2.x, n2.y};
            #pragma unroll
            for (int j = 0; j < 3; ++j) {
                const float qa = q1[i * 3 + j];
                const float qb = q2[i * 3 + j];
                #pragma unroll
                for (int k = 0; k < 4; ++k) {
                    const float x1 = __builtin_fmaf(vals[k + j], qa, 1.0f);
                    const float x2 = __builtin_fmaf(vals[k + j], qb, 1.0f);
                    const float l1 = __builtin_amdgcn_logf(x1);   // log2
                    const float l2 = __builtin_amdgcn_logf(x2);
                    const float su = l1 + l2, di = l1 - l2;       // l1^2-l2^2
                    if      (k == 0) acc0 = __builtin_fmaf(su, di, acc0);
                    else if (k == 1) acc1 = __builtin_fmaf(su, di, acc1);
                    else if (k == 2) acc2 = __builtin_fmaf(su, di, acc2);
                    else             acc3 = __builtin_fmaf(su, di, acc3);
                }
            }
        }
    };

    // depth-2 pipeline, ping-pong register sets A/B (loads issued 2 planes ahead)
    {
        float4 aA = make_float4(0.f,0.f,0.f,0.f), bA = aA, aB = aA, bB = aA;
        int q0 = pop();
        if (q0 >= 0) {
            issue(q0, aA, bA);
            int q1 = pop();
            if (q1 >= 0) issue(q1, aB, bB);
            for (;;) {
                // EVEN phase: current plane q0 in A; next in B
                stage(aA, bA);
                int q2 = pop();                 // 2-ahead into (now dead) A regs
                if (q2 >= 0) issue(q2, aA, bA);
                compute(q0);
                if (q1 < 0) break;
                // ODD phase: current plane q1 in B; next in A
                stage(aB, bB);
                int q3 = pop();
                if (q3 >= 0) issue(q3, aB, bB);
                compute(q1);
                if (q2 < 0) break;
                q0 = q2; q1 = q3;
            }
        }
    }

    // cross-phase combine: 4 partials per pixel group -> one float4 store
    Cb[t] = make_float4(acc0, acc1, acc2, acc3);
    __syncthreads();
    if (t < 64) {
        const float4 p0 = Cb[t];
        const float4 p1 = Cb[t + 64];
        const float4 p2 = Cb[t + 128];
        const float4 p3 = Cb[t + 192];
        float4 o;
        o.x = (p0.x + p1.x + p2.x + p3.x) * OSC;
        o.y = (p0.y + p1.y + p2.y + p3.y) * OSC;
        o.z = (p0.z + p1.z + p2.z + p3.z) * OSC;
        o.w = (p0.w + p1.w + p2.w + p3.w) * OSC;
        // window px (t>>3, (t&7)*4 ..+3) = flat win*256 + 4t
        float* obase = Out + (size_t)(b * COUT + co) * PIX + win * 256;
        reinterpret_cast<float4*>(obase)[t] = o;
    }
}

extern "C" void kernel_launch(void* const* d_in, const int* in_sizes, int n_in,
                              void* d_out, int out_size, void* d_ws, size_t ws_size,
                              hipStream_t stream) {
    (void)in_sizes; (void)n_in; (void)ws_size; (void)out_size;
    const float* V  = (const float*)d_in[0];   // (4,64,32,32)
    const float* Th = (const float*)d_in[1];   // (128,64,3,3)
    float* Out = (float*)d_out;                // (4,128,32,32)
    float* wg  = (float*)d_ws;                 // 4*64*4 floats = 4 KB
    ekv_rowmax<<<dim3(4 * CIN), dim3(256), 0, stream>>>(V, wg);
    ekv_main<<<dim3(4 * COUT * 4), dim3(256), 0, stream>>>(V, Th, wg, Out);
}

// Round 6
// 45.802 us; speedup vs baseline: 1.2607x; 1.0931x over previous
//
#include <hip/hip_runtime.h>

// EKV nonlinear conv2d, MI355X.
// out[b,co,h,w] = alpha * sum_{cin,i,j} sp((v-th)*inv)^2 - sp((v-th-0.1)*inv)^2
// log2-domain: e1 = 2^(v*s) * 2^(-th*s), e2 = e1*KF,
//   term = ln2^2 * (log2(1+e1)^2 - log2(1+e2)^2)
//
// v7 vs v6 (v6 FAILED, absmax 1.6e-2; only unshared-with-passing-v5 mechanic
// was the DPP horizontal exchange):
//  - Cross-lane exchange DELETED. Each lane loads its two horizontal edge
//    scalars directly from global (clamped addr, select-to-pad BEFORE exp2 --
//    same mechanism as row edges). Correct by construction; +6 exp2/plane is
//    ~8% of a log2-dominated loop. Still ZERO LDS ops in the main loop (the
//    v5 bottleneck: ds_write->lgkmcnt->ds_read chain that occupancy can't hide).
// Kept: 2048-task grid (b,co,window), XCD-bijective swizzle, popc rank-split
// of active-cin mask, depth-2 ping-pong global pipeline, LDS combine epilogue.

constexpr int CIN  = 64;
constexpr int COUT = 128;
constexpr int HW   = 32;
constexpr int PIX  = HW * HW;       // 1024

constexpr float S     = 19.235933878519512f;     // (1/0.075) * log2(e)
constexpr float KF    = 0.26359713811572677f;    // exp(-0.1/0.075)
constexpr float OSC   = 2.7025482032899376e-4f;  // alpha * ln2^2
constexpr float DELTA = 0.5718460f;              // 11/S: skip => per-term < 2^-22

// ---- pre-kernel: wg[(b*CIN+cin)*4 + w] = max V over rows 8w-1..8w+8 (0 incl. halo)
__global__ __launch_bounds__(256)
void ekv_rowmax(const float* __restrict__ V, float* __restrict__ wg)
{
    const int t = threadIdx.x;
    const int plane = blockIdx.x;               // b*CIN + cin
    __shared__ float rmax[32];
    const float4 v4 = reinterpret_cast<const float4*>(V + (size_t)plane * PIX)[t];
    float m = fmaxf(fmaxf(v4.x, v4.y), fmaxf(v4.z, v4.w));
    m = fmaxf(m, __shfl_xor(m, 1));             // reduce 8 lanes of one row
    m = fmaxf(m, __shfl_xor(m, 2));
    m = fmaxf(m, __shfl_xor(m, 4));
    if ((t & 7) == 0) rmax[t >> 3] = m;
    __syncthreads();
    if (t < 4) {
        float wm = 0.0f;                        // halo pixels are v=0 -> e=1
        #pragma unroll
        for (int rr = 0; rr < 10; ++rr) {
            const int r = 8 * t - 1 + rr;
            if (r >= 0 && r < 32) wm = fmaxf(wm, rmax[r]);
        }
        wg[plane * 4 + t] = wm;
    }
}

// ---- main kernel: task = (b, co, window); 4 waves split cin by set-bit rank
__global__ __launch_bounds__(256, 4)
void ekv_main(const float* __restrict__ V, const float* __restrict__ Th,
              const float* __restrict__ wg, float* __restrict__ Out)
{
    const int t = threadIdx.x;
    // XCD-aware bijective swizzle (nwg=2048, 8 XCDs): XCD x gets a contiguous
    // 256-task chunk = one b, 64 consecutive co -> L2-resident working set.
    const int task  = ((blockIdx.x & 7) << 8) | (blockIdx.x >> 3);
    const int win   = task & 3;                       // 8-row window 0..3
    const int co    = (task >> 2) & (COUT - 1);
    const int b     = task >> 9;
    const int phase = t >> 6;                         // cin split 0..3
    const int lane  = t & 63;

    __shared__ float  Qs[CIN * 9];        // exp2(-theta*S), block-shared
    __shared__ float4 Cb[256];            // cross-phase combine buffer

    const float* vbase = V  + (size_t)b  * CIN * PIX;
    const float* thp   = Th + (size_t)co * (CIN * 9);

    for (int i = t; i < CIN * 9; i += 256)
        Qs[i] = __builtin_amdgcn_exp2f(-thp[i] * S);

    // lane l tests cin=l: active iff window vmax >= min_k(theta)-DELTA
    float thmin = 1e30f;
    #pragma unroll
    for (int k = 0; k < 9; ++k) thmin = fminf(thmin, thp[lane * 9 + k]);
    const float wgv = wg[(size_t)(b * CIN + lane) * 4 + win];
    const unsigned long long full = __ballot(wgv >= thmin - DELTA);

    // rank-interleaved 4-way split of the active set (balanced across phases)
    const bool actv = (full >> lane) & 1ull;
    const int  rank = (int)__popcll(full & ((1ull << lane) - 1ull));
    unsigned long long mask = __ballot(actv && ((rank & 3) == phase));

    __syncthreads();    // Qs ready

    const int lr = lane >> 3;                   // 0..7
    const int lc = (lane & 7) * 4;              // 0..28
    const int r   = 8 * win + lr;               // own output/input row
    const int rm1 = (r - 1 < 0)  ? 0  : r - 1;  // clamped load rows
    const int rp1 = (r + 1 > 31) ? 31 : r + 1;
    const bool okA = (r - 1) >= 0;              // row above exists?
    const bool okC = (r + 1) <= 31;             // row below exists?
    const bool isL = (lane & 7) == 0;           // col 0 group (left image edge)
    const bool isR = (lane & 7) == 7;           // col 28 group (right image edge)
    const int  lcl = isL ? 0 : lc - 1;          // clamped edge-scalar cols
    const int  lcr = isR ? 31 : lc + 4;

    float acc0 = 0.f, acc1 = 0.f, acc2 = 0.f, acc3 = 0.f;

    auto pop = [&]() -> int {
        if (!mask) return -1;
        const int c = (int)__builtin_ctzll(mask); mask &= mask - 1; return c;
    };
    // per-plane payload: 3 rows x (float4 center + float2 (left,right) edges)
    auto issue = [&](int cin, float4& A, float4& B, float4& C,
                     float2& eA, float2& eB, float2& eC) {
        const float* src = vbase + cin * PIX;
        const float* ra = src + rm1 * HW;
        const float* rb = src + r   * HW;
        const float* rc = src + rp1 * HW;
        A = *reinterpret_cast<const float4*>(ra + lc);
        B = *reinterpret_cast<const float4*>(rb + lc);
        C = *reinterpret_cast<const float4*>(rc + lc);
        eA.x = ra[lcl]; eA.y = ra[lcr];
        eB.x = rb[lcl]; eB.y = rb[lcr];
        eC.x = rc[lcl]; eC.y = rc[lcr];
    };
    // row -> 6 exp'd values; pad (v=0 -> e=1) selected BEFORE exp2
    auto rowv = [&](const float4& x, const float2& e, bool ok, float* vals) {
        vals[0] = __builtin_amdgcn_exp2f(((ok && !isL) ? e.x : 0.f) * S);
        vals[1] = __builtin_amdgcn_exp2f((ok ? x.x : 0.f) * S);
        vals[2] = __builtin_amdgcn_exp2f((ok ? x.y : 0.f) * S);
        vals[3] = __builtin_amdgcn_exp2f((ok ? x.z : 0.f) * S);
        vals[4] = __builtin_amdgcn_exp2f((ok ? x.w : 0.f) * S);
        vals[5] = __builtin_amdgcn_exp2f(((ok && !isR) ? e.y : 0.f) * S);
    };
    auto compute = [&](int cin, const float4& A, const float4& B, const float4& C,
                       const float2& eA, const float2& eB, const float2& eC) {
        float q1[9], q2[9];
        #pragma unroll
        for (int k = 0; k < 9; ++k) {
            q1[k] = Qs[cin * 9 + k];            // conflict-free broadcast reads
            q2[k] = q1[k] * KF;
        }
        float vr[3][6];
        rowv(A, eA, okA, vr[0]);
        rowv(B, eB, true, vr[1]);
        rowv(C, eC, okC, vr[2]);
        #pragma unroll
        for (int i = 0; i < 3; ++i) {
            #pragma unroll
            for (int j = 0; j < 3; ++j) {
                const float qa = q1[i * 3 + j];
                const float qb = q2[i * 3 + j];
                #pragma unroll
                for (int k = 0; k < 4; ++k) {
                    const float x1 = __builtin_fmaf(vr[i][k + j], qa, 1.0f);
                    const float x2 = __builtin_fmaf(vr[i][k + j], qb, 1.0f);
                    const float l1 = __builtin_amdgcn_logf(x1);   // log2
                    const float l2 = __builtin_amdgcn_logf(x2);
                    const float su = l1 + l2, di = l1 - l2;       // l1^2-l2^2
                    if      (k == 0) acc0 = __builtin_fmaf(su, di, acc0);
                    else if (k == 1) acc1 = __builtin_fmaf(su, di, acc1);
                    else if (k == 2) acc2 = __builtin_fmaf(su, di, acc2);
                    else             acc3 = __builtin_fmaf(su, di, acc3);
                }
            }
        }
    };

    // depth-2 pipeline, ping-pong register sets A/B (loads issued 2 planes ahead)
    {
        float4 aA = make_float4(0.f,0.f,0.f,0.f), bA = aA, cA = aA;
        float4 aB = aA, bB = aA, cB = aA;
        float2 eaA = make_float2(0.f,0.f), ebA = eaA, ecA = eaA;
        float2 eaB = eaA, ebB = eaA, ecB = eaA;
        int q0 = pop();
        if (q0 >= 0) {
            issue(q0, aA, bA, cA, eaA, ebA, ecA);
            int q1 = pop();
            if (q1 >= 0) issue(q1, aB, bB, cB, eaB, ebB, ecB);
            for (;;) {
                // EVEN: current plane q0 in set A; 2-ahead issued into dead A regs
                {
                    const float4 xa = aA, xb = bA, xc = cA;
                    const float2 ya = eaA, yb = ebA, yc = ecA;
                    int q2 = pop();
                    if (q2 >= 0) issue(q2, aA, bA, cA, eaA, ebA, ecA);
                    compute(q0, xa, xb, xc, ya, yb, yc);
                    if (q1 < 0) break;
                    q0 = q2;
                }
                // ODD: current plane q1 in set B
                {
                    const float4 xa = aB, xb = bB, xc = cB;
                    const float2 ya = eaB, yb = ebB, yc = ecB;
                    int q3 = pop();
                    if (q3 >= 0) issue(q3, aB, bB, cB, eaB, ebB, ecB);
                    compute(q1, xa, xb, xc, ya, yb, yc);
                    if (q0 < 0) break;
                    q1 = q3;
                }
            }
        }
    }

    // cross-phase combine: 4 partials per pixel group -> one float4 store
    Cb[t] = make_float4(acc0, acc1, acc2, acc3);
    __syncthreads();
    if (t < 64) {
        const float4 p0 = Cb[t];
        const float4 p1 = Cb[t + 64];
        const float4 p2 = Cb[t + 128];
        const float4 p3 = Cb[t + 192];
        float4 o;
        o.x = (p0.x + p1.x + p2.x + p3.x) * OSC;
        o.y = (p0.y + p1.y + p2.y + p3.y) * OSC;
        o.z = (p0.z + p1.z + p2.z + p3.z) * OSC;
        o.w = (p0.w + p1.w + p2.w + p3.w) * OSC;
        // window px (t>>3, (t&7)*4 ..+3) = flat win*256 + 4t
        float* obase = Out + (size_t)(b * COUT + co) * PIX + win * 256;
        reinterpret_cast<float4*>(obase)[t] = o;
    }
}

extern "C" void kernel_launch(void* const* d_in, const int* in_sizes, int n_in,
                              void* d_out, int out_size, void* d_ws, size_t ws_size,
                              hipStream_t stream) {
    (void)in_sizes; (void)n_in; (void)ws_size; (void)out_size;
    const float* V  = (const float*)d_in[0];   // (4,64,32,32)
    const float* Th = (const float*)d_in[1];   // (128,64,3,3)
    float* Out = (float*)d_out;                // (4,128,32,32)
    float* wg  = (float*)d_ws;                 // 4*64*4 floats = 4 KB
    ekv_rowmax<<<dim3(4 * CIN), dim3(256), 0, stream>>>(V, wg);
    ekv_main<<<dim3(4 * COUT * 4), dim3(256), 0, stream>>>(V, Th, wg, Out);
}

// Round 7
// 29.246 us; speedup vs baseline: 1.9743x; 1.5661x over previous
//
#include <hip/hip_runtime.h>

// EKV nonlinear conv2d, MI355X.
// out[b,co,h,w] = alpha * sum_{cin,i,j} sp((v-th)*inv)^2 - sp((v-th-0.1)*inv)^2
// log2-domain: e1 = 2^(v*s) * 2^(-th*s), e2 = e1*KF,
//   term = ln2^2 * (log2(1+e1)^2 - log2(1+e2)^2)
//
// v8 vs 45.8us v7 (post-mortem: conflicts=0, FETCH=compulsory, VALUBusy 45%
// => issue-bound on 90 trans-ops/plane; and theta's 9 taps span ~1.5 while
// the skip margin is 0.57 => planes are active via ~1.2 of 9 taps only):
//  - PER-TAP skip: T[cin] = 2^(-8 - vmax*S) precomputed block-level (all 4
//    waves share the window). Tap k live iff q[k] >= T -- wave-uniform
//    compare -> coherent execz branch. Dead tap saves 8 log2; dead row
//    (3 dead taps) also saves its 6 exp2. ~1100 -> ~300 cyc/plane.
//    Bound per skipped term: (1.443*2^-8)^2 ~ 3.2e-5 raw; total < 5e-6 out.
//  - Wave-skip margin widened 11 -> 8 (DELTA = 8/S), same bound family.
//  - q2 (=q*KF) computed only for live taps.
// Kept from v7: zero main-loop LDS, register 3-row window + direct edge
// scalar loads (pad selected before exp2), depth-2 ping-pong pipeline,
// 2048-task grid (b,co,window), XCD-bijective swizzle, popc rank-split,
// LDS combine epilogue.

constexpr int CIN  = 64;
constexpr int COUT = 128;
constexpr int HW   = 32;
constexpr int PIX  = HW * HW;       // 1024

constexpr float S     = 19.235933878519512f;     // (1/0.075) * log2(e)
constexpr float KF    = 0.26359713811572677f;    // exp(-0.1/0.075)
constexpr float OSC   = 2.7025482032899376e-4f;  // alpha * ln2^2
constexpr float DELTA = 0.4158883f;              // 8/S (rounded down = conservative)

// ---- pre-kernel: wg[(b*CIN+cin)*4 + w] = max V over rows 8w-1..8w+8 (0 incl. halo)
__global__ __launch_bounds__(256)
void ekv_rowmax(const float* __restrict__ V, float* __restrict__ wg)
{
    const int t = threadIdx.x;
    const int plane = blockIdx.x;               // b*CIN + cin
    __shared__ float rmax[32];
    const float4 v4 = reinterpret_cast<const float4*>(V + (size_t)plane * PIX)[t];
    float m = fmaxf(fmaxf(v4.x, v4.y), fmaxf(v4.z, v4.w));
    m = fmaxf(m, __shfl_xor(m, 1));             // reduce 8 lanes of one row
    m = fmaxf(m, __shfl_xor(m, 2));
    m = fmaxf(m, __shfl_xor(m, 4));
    if ((t & 7) == 0) rmax[t >> 3] = m;
    __syncthreads();
    if (t < 4) {
        float wm = 0.0f;                        // halo pixels are v=0 -> e=1
        #pragma unroll
        for (int rr = 0; rr < 10; ++rr) {
            const int r = 8 * t - 1 + rr;
            if (r >= 0 && r < 32) wm = fmaxf(wm, rmax[r]);
        }
        wg[plane * 4 + t] = wm;
    }
}

// ---- main kernel: task = (b, co, window); 4 waves split cin by set-bit rank
__global__ __launch_bounds__(256, 4)
void ekv_main(const float* __restrict__ V, const float* __restrict__ Th,
              const float* __restrict__ wg, float* __restrict__ Out)
{
    const int t = threadIdx.x;
    // XCD-aware bijective swizzle (nwg=2048, 8 XCDs): XCD x gets a contiguous
    // 256-task chunk = one b, 64 consecutive co -> L2-resident working set.
    const int task  = ((blockIdx.x & 7) << 8) | (blockIdx.x >> 3);
    const int win   = task & 3;                       // 8-row window 0..3
    const int co    = (task >> 2) & (COUT - 1);
    const int b     = task >> 9;
    const int phase = t >> 6;                         // cin split 0..3
    const int lane  = t & 63;

    __shared__ float  Qs[CIN * 9];        // exp2(-theta*S), block-shared
    __shared__ float  Ts[CIN];            // per-cin tap threshold 2^(-8 - vmax*S)
    __shared__ float4 Cb[256];            // cross-phase combine buffer

    const float* vbase = V  + (size_t)b  * CIN * PIX;
    const float* thp   = Th + (size_t)co * (CIN * 9);

    for (int i = t; i < CIN * 9; i += 256)
        Qs[i] = __builtin_amdgcn_exp2f(-thp[i] * S);

    // lane l tests cin=l: active iff window vmax >= min_k(theta)-DELTA
    float thmin = 1e30f;
    #pragma unroll
    for (int k = 0; k < 9; ++k) thmin = fminf(thmin, thp[lane * 9 + k]);
    const float wgv = wg[(size_t)(b * CIN + lane) * 4 + win];
    const unsigned long long full = __ballot(wgv >= thmin - DELTA);

    // block-level tap thresholds (all 4 waves share this window); t<64 covers CIN
    if (t < CIN) Ts[t] = __builtin_amdgcn_exp2f(-8.0f - wgv * S);

    // rank-interleaved 4-way split of the active set (balanced across phases)
    const bool actv = (full >> lane) & 1ull;
    const int  rank = (int)__popcll(full & ((1ull << lane) - 1ull));
    unsigned long long mask = __ballot(actv && ((rank & 3) == phase));

    __syncthreads();    // Qs, Ts ready

    const int lr = lane >> 3;                   // 0..7
    const int lc = (lane & 7) * 4;              // 0..28
    const int r   = 8 * win + lr;               // own output/input row
    const int rm1 = (r - 1 < 0)  ? 0  : r - 1;  // clamped load rows
    const int rp1 = (r + 1 > 31) ? 31 : r + 1;
    const bool okA = (r - 1) >= 0;              // row above exists?
    const bool okC = (r + 1) <= 31;             // row below exists?
    const bool isL = (lane & 7) == 0;           // col 0 group (left image edge)
    const bool isR = (lane & 7) == 7;           // col 28 group (right image edge)
    const int  lcl = isL ? 0 : lc - 1;          // clamped edge-scalar cols
    const int  lcr = isR ? 31 : lc + 4;

    float acc0 = 0.f, acc1 = 0.f, acc2 = 0.f, acc3 = 0.f;

    auto pop = [&]() -> int {
        if (!mask) return -1;
        const int c = (int)__builtin_ctzll(mask); mask &= mask - 1; return c;
    };
    // per-plane payload: 3 rows x (float4 center + float2 (left,right) edges)
    auto issue = [&](int cin, float4& A, float4& B, float4& C,
                     float2& eA, float2& eB, float2& eC) {
        const float* src = vbase + cin * PIX;
        const float* ra = src + rm1 * HW;
        const float* rb = src + r   * HW;
        const float* rc = src + rp1 * HW;
        A = *reinterpret_cast<const float4*>(ra + lc);
        B = *reinterpret_cast<const float4*>(rb + lc);
        C = *reinterpret_cast<const float4*>(rc + lc);
        eA.x = ra[lcl]; eA.y = ra[lcr];
        eB.x = rb[lcl]; eB.y = rb[lcr];
        eC.x = rc[lcl]; eC.y = rc[lcr];
    };
    // row -> 6 exp'd values; pad (v=0 -> e=1) selected BEFORE exp2
    auto rowv = [&](const float4& x, const float2& e, bool ok, float* vals) {
        vals[0] = __builtin_amdgcn_exp2f(((ok && !isL) ? e.x : 0.f) * S);
        vals[1] = __builtin_amdgcn_exp2f((ok ? x.x : 0.f) * S);
        vals[2] = __builtin_amdgcn_exp2f((ok ? x.y : 0.f) * S);
        vals[3] = __builtin_amdgcn_exp2f((ok ? x.z : 0.f) * S);
        vals[4] = __builtin_amdgcn_exp2f((ok ? x.w : 0.f) * S);
        vals[5] = __builtin_amdgcn_exp2f(((ok && !isR) ? e.y : 0.f) * S);
    };
    auto compute = [&](int cin, const float4& A, const float4& B, const float4& C,
                       const float2& eA, const float2& eB, const float2& eC) {
        const float  T  = Ts[cin];              // broadcast reads, wave-uniform
        const float* qp = &Qs[cin * 9];
        #pragma unroll
        for (int i = 0; i < 3; ++i) {
            const float q0 = qp[i * 3 + 0];
            const float q1 = qp[i * 3 + 1];
            const float q2 = qp[i * 3 + 2];
            if (fmaxf(fmaxf(q0, q1), q2) < T) continue;   // whole tap-row dead
            float vals[6];
            if      (i == 0) rowv(A, eA, okA, vals);
            else if (i == 1) rowv(B, eB, true, vals);
            else             rowv(C, eC, okC, vals);
            #pragma unroll
            for (int j = 0; j < 3; ++j) {
                const float qa = (j == 0) ? q0 : (j == 1) ? q1 : q2;
                if (qa < T) continue;                     // tap dead
                const float qb = qa * KF;
                #pragma unroll
                for (int k = 0; k < 4; ++k) {
                    const float x1 = __builtin_fmaf(vals[k + j], qa, 1.0f);
                    const float x2 = __builtin_fmaf(vals[k + j], qb, 1.0f);
                    const float l1 = __builtin_amdgcn_logf(x1);   // log2
                    const float l2 = __builtin_amdgcn_logf(x2);
                    const float su = l1 + l2, di = l1 - l2;       // l1^2-l2^2
                    if      (k == 0) acc0 = __builtin_fmaf(su, di, acc0);
                    else if (k == 1) acc1 = __builtin_fmaf(su, di, acc1);
                    else if (k == 2) acc2 = __builtin_fmaf(su, di, acc2);
                    else             acc3 = __builtin_fmaf(su, di, acc3);
                }
            }
        }
    };

    // depth-2 pipeline, ping-pong register sets A/B (loads issued 2 planes ahead)
    {
        float4 aA = make_float4(0.f,0.f,0.f,0.f), bA = aA, cA = aA;
        float4 aB = aA, bB = aA, cB = aA;
        float2 eaA = make_float2(0.f,0.f), ebA = eaA, ecA = eaA;
        float2 eaB = eaA, ebB = eaA, ecB = eaA;
        int q0 = pop();
        if (q0 >= 0) {
            issue(q0, aA, bA, cA, eaA, ebA, ecA);
            int q1 = pop();
            if (q1 >= 0) issue(q1, aB, bB, cB, eaB, ebB, ecB);
            for (;;) {
                // EVEN: current plane q0 in set A; 2-ahead issued into dead A regs
                {
                    const float4 xa = aA, xb = bA, xc = cA;
                    const float2 ya = eaA, yb = ebA, yc = ecA;
                    int q2 = pop();
                    if (q2 >= 0) issue(q2, aA, bA, cA, eaA, ebA, ecA);
                    compute(q0, xa, xb, xc, ya, yb, yc);
                    if (q1 < 0) break;
                    q0 = q2;
                }
                // ODD: current plane q1 in set B
                {
                    const float4 xa = aB, xb = bB, xc = cB;
                    const float2 ya = eaB, yb = ebB, yc = ecB;
                    int q3 = pop();
                    if (q3 >= 0) issue(q3, aB, bB, cB, eaB, ebB, ecB);
                    compute(q1, xa, xb, xc, ya, yb, yc);
                    if (q0 < 0) break;
                    q1 = q3;
                }
            }
        }
    }

    // cross-phase combine: 4 partials per pixel group -> one float4 store
    Cb[t] = make_float4(acc0, acc1, acc2, acc3);
    __syncthreads();
    if (t < 64) {
        const float4 p0 = Cb[t];
        const float4 p1 = Cb[t + 64];
        const float4 p2 = Cb[t + 128];
        const float4 p3 = Cb[t + 192];
        float4 o;
        o.x = (p0.x + p1.x + p2.x + p3.x) * OSC;
        o.y = (p0.y + p1.y + p2.y + p3.y) * OSC;
        o.z = (p0.z + p1.z + p2.z + p3.z) * OSC;
        o.w = (p0.w + p1.w + p2.w + p3.w) * OSC;
        // window px (t>>3, (t&7)*4 ..+3) = flat win*256 + 4t
        float* obase = Out + (size_t)(b * COUT + co) * PIX + win * 256;
        reinterpret_cast<float4*>(obase)[t] = o;
    }
}

extern "C" void kernel_launch(void* const* d_in, const int* in_sizes, int n_in,
                              void* d_out, int out_size, void* d_ws, size_t ws_size,
                              hipStream_t stream) {
    (void)in_sizes; (void)n_in; (void)ws_size; (void)out_size;
    const float* V  = (const float*)d_in[0];   // (4,64,32,32)
    const float* Th = (const float*)d_in[1];   // (128,64,3,3)
    float* Out = (float*)d_out;                // (4,128,32,32)
    float* wg  = (float*)d_ws;                 // 4*64*4 floats = 4 KB
    ekv_rowmax<<<dim3(4 * CIN), dim3(256), 0, stream>>>(V, wg);
    ekv_main<<<dim3(4 * COUT * 4), dim3(256), 0, stream>>>(V, Th, wg, Out);
}

// Round 8
// 25.719 us; speedup vs baseline: 2.2450x; 1.1371x over previous
//
#include <hip/hip_runtime.h>

// EKV nonlinear conv2d, MI355X.
// out[b,co,h,w] = alpha * sum_{cin,i,j} sp((v-th)*inv)^2 - sp((v-th-0.1)*inv)^2
// log2-domain: e1 = 2^(v*s) * 2^(-th*s), e2 = e1*KF,
//   term = ln2^2 * (log2(1+e1)^2 - log2(1+e2)^2)
//
// v9 vs 29.2us v8 (post-tap-skip: compute shrank ~3x but 9 VMEM/plane and the
// static rank-split didn't shrink with it; work per plane now varies 1..9
// live taps -> wave imbalance):
//  - Dead-ROW load elimination: rlm[cin] 3-bit row-live mask ((cin,win)-
//    uniform, built in prologue from theta row-minima). issue() loads only
//    live rows -> ~3.3 VMEM/plane avg instead of 9. Numerically identical:
//    skipped rows are rows all of whose taps were already tap-skipped.
//  - LDS atomic work queue replaces static rank-split: compacted active list
//    + head counter; lane-0 atomicAdd pop + __shfl broadcast (wave ops only,
//    no DPP). Waves self-balance tap-weighted load within the block.
//  - Prologue trim: only wave 0 loads the 9 theta scalars / builds
//    Ts/rlm/list (waves 1-3 drop 9 VMEM each).
// Kept from v8: per-tap skip vs Ts, zero main-loop LDS traffic pattern
// (broadcast reads only), register 3-row window + direct edge scalars (pad
// selected before exp2), depth-2 ping-pong pipeline, 2048-task grid
// (b,co,window), XCD-bijective swizzle, LDS combine epilogue.

constexpr int CIN  = 64;
constexpr int COUT = 128;
constexpr int HW   = 32;
constexpr int PIX  = HW * HW;       // 1024

constexpr float S     = 19.235933878519512f;     // (1/0.075) * log2(e)
constexpr float KF    = 0.26359713811572677f;    // exp(-0.1/0.075)
constexpr float OSC   = 2.7025482032899376e-4f;  // alpha * ln2^2
constexpr float DELTA = 0.4158883f;              // ~8/S (rounded down = conservative)

// ---- pre-kernel: wg[(b*CIN+cin)*4 + w] = max V over rows 8w-1..8w+8 (0 incl. halo)
__global__ __launch_bounds__(256)
void ekv_rowmax(const float* __restrict__ V, float* __restrict__ wg)
{
    const int t = threadIdx.x;
    const int plane = blockIdx.x;               // b*CIN + cin
    __shared__ float rmax[32];
    const float4 v4 = reinterpret_cast<const float4*>(V + (size_t)plane * PIX)[t];
    float m = fmaxf(fmaxf(v4.x, v4.y), fmaxf(v4.z, v4.w));
    m = fmaxf(m, __shfl_xor(m, 1));             // reduce 8 lanes of one row
    m = fmaxf(m, __shfl_xor(m, 2));
    m = fmaxf(m, __shfl_xor(m, 4));
    if ((t & 7) == 0) rmax[t >> 3] = m;
    __syncthreads();
    if (t < 4) {
        float wm = 0.0f;                        // halo pixels are v=0 -> e=1
        #pragma unroll
        for (int rr = 0; rr < 10; ++rr) {
            const int r = 8 * t - 1 + rr;
            if (r >= 0 && r < 32) wm = fmaxf(wm, rmax[r]);
        }
        wg[plane * 4 + t] = wm;
    }
}

// ---- main kernel: task = (b, co, window); 4 waves pull planes off a queue
__global__ __launch_bounds__(256, 4)
void ekv_main(const float* __restrict__ V, const float* __restrict__ Th,
              const float* __restrict__ wg, float* __restrict__ Out)
{
    const int t = threadIdx.x;
    // XCD-aware bijective swizzle (nwg=2048, 8 XCDs): XCD x gets a contiguous
    // 256-task chunk = one b, 64 consecutive co -> L2-resident working set.
    const int task  = ((blockIdx.x & 7) << 8) | (blockIdx.x >> 3);
    const int win   = task & 3;                       // 8-row window 0..3
    const int co    = (task >> 2) & (COUT - 1);
    const int b     = task >> 9;
    const int lane  = t & 63;

    __shared__ float    Qs[CIN * 9];   // exp2(-theta*S), block-shared
    __shared__ float    Ts[CIN];       // per-cin tap threshold 2^(-8 - vmax*S)
    __shared__ unsigned rlm[CIN];      // 3-bit row-live mask per cin
    __shared__ int      listS[80];     // compacted active-cin list (pad for OOB sel)
    __shared__ int      nactS, headS;
    __shared__ float4   Cb[256];       // cross-phase combine buffer

    const float* vbase = V  + (size_t)b  * CIN * PIX;
    const float* thp   = Th + (size_t)co * (CIN * 9);

    for (int i = t; i < CIN * 9; i += 256)
        Qs[i] = __builtin_amdgcn_exp2f(-thp[i] * S);

    // wave 0 builds thresholds, row-live masks, and the compacted queue
    if (t < CIN) {
        const float wgv = wg[(size_t)(b * CIN + t) * 4 + win];
        const float lim = wgv + DELTA;
        float m0 = 1e30f, m1 = 1e30f, m2 = 1e30f;
        #pragma unroll
        for (int k = 0; k < 3; ++k) m0 = fminf(m0, thp[t * 9 + k]);
        #pragma unroll
        for (int k = 3; k < 6; ++k) m1 = fminf(m1, thp[t * 9 + k]);
        #pragma unroll
        for (int k = 6; k < 9; ++k) m2 = fminf(m2, thp[t * 9 + k]);
        const unsigned rm = (m0 <= lim ? 1u : 0u) | (m1 <= lim ? 2u : 0u)
                          | (m2 <= lim ? 4u : 0u);
        rlm[t] = rm;
        Ts[t]  = __builtin_amdgcn_exp2f(-8.0f - wgv * S);
        const bool act = rm != 0u;
        const unsigned long long bal = __ballot(act);        // whole wave 0
        const int rank = (int)__popcll(bal & ((1ull << t) - 1ull));
        if (act) listS[rank] = t;
        if (t == 0) { nactS = (int)__popcll(bal); headS = 0; }
    }

    __syncthreads();    // Qs, Ts, rlm, queue ready
    const int nact = nactS;

    const int lr = lane >> 3;                   // 0..7
    const int lc = (lane & 7) * 4;              // 0..28
    const int r   = 8 * win + lr;               // own output/input row
    const int rm1 = (r - 1 < 0)  ? 0  : r - 1;  // clamped load rows
    const int rp1 = (r + 1 > 31) ? 31 : r + 1;
    const bool okA = (r - 1) >= 0;              // row above exists?
    const bool okC = (r + 1) <= 31;             // row below exists?
    const bool isL = (lane & 7) == 0;           // col 0 group (left image edge)
    const bool isR = (lane & 7) == 7;           // col 28 group (right image edge)
    const int  lcl = isL ? 0 : lc - 1;          // clamped edge-scalar cols
    const int  lcr = isR ? 31 : lc + 4;

    float acc0 = 0.f, acc1 = 0.f, acc2 = 0.f, acc3 = 0.f;

    // self-balancing queue pop: lane 0 takes a ticket, wave broadcasts it
    auto pop = [&]() -> int {
        int idx = 0;
        if (lane == 0) idx = atomicAdd(&headS, 1);
        idx = __shfl(idx, 0);
        return (idx < nact) ? listS[idx] : -1;
    };
    // per-plane payload: live rows only (rlm is (cin)-uniform -> coherent branch)
    auto issue = [&](int cin, float4& A, float4& B, float4& C,
                     float2& eA, float2& eB, float2& eC) {
        const unsigned m = rlm[cin];
        const float* src = vbase + cin * PIX;
        if (m & 1u) {
            const float* ra = src + rm1 * HW;
            A = *reinterpret_cast<const float4*>(ra + lc);
            eA.x = ra[lcl]; eA.y = ra[lcr];
        }
        if (m & 2u) {
            const float* rb = src + r * HW;
            B = *reinterpret_cast<const float4*>(rb + lc);
            eB.x = rb[lcl]; eB.y = rb[lcr];
        }
        if (m & 4u) {
            const float* rc = src + rp1 * HW;
            C = *reinterpret_cast<const float4*>(rc + lc);
            eC.x = rc[lcl]; eC.y = rc[lcr];
        }
    };
    // row -> 6 exp'd values; pad (v=0 -> e=1) selected BEFORE exp2
    auto rowv = [&](const float4& x, const float2& e, bool ok, float* vals) {
        vals[0] = __builtin_amdgcn_exp2f(((ok && !isL) ? e.x : 0.f) * S);
        vals[1] = __builtin_amdgcn_exp2f((ok ? x.x : 0.f) * S);
        vals[2] = __builtin_amdgcn_exp2f((ok ? x.y : 0.f) * S);
        vals[3] = __builtin_amdgcn_exp2f((ok ? x.z : 0.f) * S);
        vals[4] = __builtin_amdgcn_exp2f((ok ? x.w : 0.f) * S);
        vals[5] = __builtin_amdgcn_exp2f(((ok && !isR) ? e.y : 0.f) * S);
    };
    auto compute = [&](int cin, const float4& A, const float4& B, const float4& C,
                       const float2& eA, const float2& eB, const float2& eC) {
        const float    T  = Ts[cin];            // broadcast reads, wave-uniform
        const unsigned m  = rlm[cin];
        const float*   qp = &Qs[cin * 9];
        #pragma unroll
        for (int i = 0; i < 3; ++i) {
            if (!((m >> i) & 1u)) continue;               // tap-row dead
            const float q0 = qp[i * 3 + 0];
            const float q1 = qp[i * 3 + 1];
            const float q2 = qp[i * 3 + 2];
            float vals[6];
            if      (i == 0) rowv(A, eA, okA, vals);
            else if (i == 1) rowv(B, eB, true, vals);
            else             rowv(C, eC, okC, vals);
            #pragma unroll
            for (int j = 0; j < 3; ++j) {
                const float qa = (j == 0) ? q0 : (j == 1) ? q1 : q2;
                if (qa < T) continue;                     // tap dead
                const float qb = qa * KF;
                #pragma unroll
                for (int k = 0; k < 4; ++k) {
                    const float x1 = __builtin_fmaf(vals[k + j], qa, 1.0f);
                    const float x2 = __builtin_fmaf(vals[k + j], qb, 1.0f);
                    const float l1 = __builtin_amdgcn_logf(x1);   // log2
                    const float l2 = __builtin_amdgcn_logf(x2);
                    const float su = l1 + l2, di = l1 - l2;       // l1^2-l2^2
                    if      (k == 0) acc0 = __builtin_fmaf(su, di, acc0);
                    else if (k == 1) acc1 = __builtin_fmaf(su, di, acc1);
                    else if (k == 2) acc2 = __builtin_fmaf(su, di, acc2);
                    else             acc3 = __builtin_fmaf(su, di, acc3);
                }
            }
        }
    };

    // depth-2 pipeline, ping-pong register sets A/B (loads issued 2 planes ahead)
    {
        float4 aA = make_float4(0.f,0.f,0.f,0.f), bA = aA, cA = aA;
        float4 aB = aA, bB = aA, cB = aA;
        float2 eaA = make_float2(0.f,0.f), ebA = eaA, ecA = eaA;
        float2 eaB = eaA, ebB = eaA, ecB = eaA;
        int q0 = pop();
        if (q0 >= 0) {
            issue(q0, aA, bA, cA, eaA, ebA, ecA);
            int q1 = pop();
            if (q1 >= 0) issue(q1, aB, bB, cB, eaB, ebB, ecB);
            for (;;) {
                // EVEN: current plane q0 in set A; 2-ahead issued into dead A regs
                {
                    const float4 xa = aA, xb = bA, xc = cA;
                    const float2 ya = eaA, yb = ebA, yc = ecA;
                    int q2 = (q1 >= 0) ? pop() : -1;
                    if (q2 >= 0) issue(q2, aA, bA, cA, eaA, ebA, ecA);
                    compute(q0, xa, xb, xc, ya, yb, yc);
                    if (q1 < 0) break;
                    q0 = q2;
                }
                // ODD: current plane q1 in set B
                {
                    const float4 xa = aB, xb = bB, xc = cB;
                    const float2 ya = eaB, yb = ebB, yc = ecB;
                    int q3 = (q0 >= 0) ? pop() : -1;
                    if (q3 >= 0) issue(q3, aB, bB, cB, eaB, ebB, ecB);
                    compute(q1, xa, xb, xc, ya, yb, yc);
                    if (q0 < 0) break;
                    q1 = q3;
                }
            }
        }
    }

    // cross-phase combine: 4 partials per pixel group -> one float4 store
    Cb[t] = make_float4(acc0, acc1, acc2, acc3);
    __syncthreads();
    if (t < 64) {
        const float4 p0 = Cb[t];
        const float4 p1 = Cb[t + 64];
        const float4 p2 = Cb[t + 128];
        const float4 p3 = Cb[t + 192];
        float4 o;
        o.x = (p0.x + p1.x + p2.x + p3.x) * OSC;
        o.y = (p0.y + p1.y + p2.y + p3.y) * OSC;
        o.z = (p0.z + p1.z + p2.z + p3.z) * OSC;
        o.w = (p0.w + p1.w + p2.w + p3.w) * OSC;
        // window px (t>>3, (t&7)*4 ..+3) = flat win*256 + 4t
        float* obase = Out + (size_t)(b * COUT + co) * PIX + win * 256;
        reinterpret_cast<float4*>(obase)[t] = o;
    }
}

extern "C" void kernel_launch(void* const* d_in, const int* in_sizes, int n_in,
                              void* d_out, int out_size, void* d_ws, size_t ws_size,
                              hipStream_t stream) {
    (void)in_sizes; (void)n_in; (void)ws_size; (void)out_size;
    const float* V  = (const float*)d_in[0];   // (4,64,32,32)
    const float* Th = (const float*)d_in[1];   // (128,64,3,3)
    float* Out = (float*)d_out;                // (4,128,32,32)
    float* wg  = (float*)d_ws;                 // 4*64*4 floats = 4 KB
    ekv_rowmax<<<dim3(4 * CIN), dim3(256), 0, stream>>>(V, wg);
    ekv_main<<<dim3(4 * COUT * 4), dim3(256), 0, stream>>>(V, Th, wg, Out);
}

// Round 9
// 24.125 us; speedup vs baseline: 2.3934x; 1.0661x over previous
//
#include <hip/hip_runtime.h>

// EKV nonlinear conv2d, MI355X.
// out[b,co,h,w] = alpha * sum_{cin,i,j} sp((v-th)*inv)^2 - sp((v-th-0.1)*inv)^2
// log2-domain: e1 = 2^(v*s) * 2^(-th*s), e2 = e1*KF,
//   term = ln2^2 * (log2(1+e1)^2 - log2(1+e2)^2)
//
// v10 vs 25.7us v9: at per-window DELTA the active set is ~6/64 planes, so
// real work is <1us and per-block overhead dominates (Qs prologue = 576
// theta loads + 576 exp2 per block for ~6 used planes; combine barriers;
// 2048 blocks). Restructure:
//  - Register/shuffle metadata: lane l owns cin l -- loads its 9 theta, its
//    wgv, builds 9-bit tap-live mask tlm and q[k]=exp2(-th*S) in REGISTERS.
//    Per plane: __shfl(tlm,cin) + 9x __shfl(q[k],cin). ZERO LDS, ZERO
//    barriers anywhere in the kernel.
//  - block=(b,co) (grid 512), wave w owns window w: prologue amortized 4x,
//    each wave stores its own 256 px directly -- combine epilogue deleted.
//  - Skip margin M: 8 -> 5 (DELTA=5/S). Worst-case skipped-term bound:
//    576*OSC*(1.443*2^-5)^2 ~ 3.2e-4 < 7.47e-4 threshold (M=4 would exceed
//    it; M=5 is the safe floor). Expected absmax ~8e-6.
// Kept: tap-level skip, dead-row load elimination (now via tlm row bits),
// register 3-row window + direct edge scalars (pad selected before exp2),
// depth-2 ping-pong pipeline, XCD-bijective swizzle (512%8==0), rowmax
// pre-kernel.

constexpr int CIN  = 64;
constexpr int COUT = 128;
constexpr int HW   = 32;
constexpr int PIX  = HW * HW;       // 1024

constexpr float S     = 19.235933878519512f;     // (1/0.075) * log2(e)
constexpr float KF    = 0.26359713811572677f;    // exp(-0.1/0.075)
constexpr float OSC   = 2.7025482032899376e-4f;  // alpha * ln2^2
constexpr float DELTA = 0.2599401f;              // 5/S rounded UP (conservative)

// ---- pre-kernel: wg[(b*CIN+cin)*4 + w] = max V over rows 8w-1..8w+8 (0 incl. halo)
__global__ __launch_bounds__(256)
void ekv_rowmax(const float* __restrict__ V, float* __restrict__ wg)
{
    const int t = threadIdx.x;
    const int plane = blockIdx.x;               // b*CIN + cin
    __shared__ float rmax[32];
    const float4 v4 = reinterpret_cast<const float4*>(V + (size_t)plane * PIX)[t];
    float m = fmaxf(fmaxf(v4.x, v4.y), fmaxf(v4.z, v4.w));
    m = fmaxf(m, __shfl_xor(m, 1));             // reduce 8 lanes of one row
    m = fmaxf(m, __shfl_xor(m, 2));
    m = fmaxf(m, __shfl_xor(m, 4));
    if ((t & 7) == 0) rmax[t >> 3] = m;
    __syncthreads();
    if (t < 4) {
        float wm = 0.0f;                        // halo pixels are v=0 -> e=1
        #pragma unroll
        for (int rr = 0; rr < 10; ++rr) {
            const int r = 8 * t - 1 + rr;
            if (r >= 0 && r < 32) wm = fmaxf(wm, rmax[r]);
        }
        wg[plane * 4 + t] = wm;
    }
}

// ---- main kernel: block = (b, co); wave w owns 8-row window w; lane l owns
// cin l's metadata. No LDS, no barriers.
__global__ __launch_bounds__(256, 4)
void ekv_main(const float* __restrict__ V, const float* __restrict__ Th,
              const float* __restrict__ wg, float* __restrict__ Out)
{
    const int t = threadIdx.x;
    // XCD-aware bijective swizzle (nwg=512, 8 XCDs): XCD x gets a contiguous
    // 64-task chunk (one b, 64 consecutive co) -> L2-resident working set.
    const int task = ((blockIdx.x & 7) << 6) | (blockIdx.x >> 3);
    const int co   = task & (COUT - 1);
    const int b    = task >> 7;
    const int w    = t >> 6;                    // wave = window 0..3
    const int lane = t & 63;

    const float* vbase = V  + (size_t)b  * CIN * PIX;
    const float* thp   = Th + (size_t)co * (CIN * 9);

    // ---- register prologue: lane l = cin l ----
    float th[9];
    #pragma unroll
    for (int k = 0; k < 9; ++k) th[k] = thp[lane * 9 + k];
    const float wgv = wg[(size_t)(b * CIN + lane) * 4 + w];
    const float lim = wgv + DELTA;
    unsigned tlm = 0u;                          // bit 3i+j: tap (i,j) live
    #pragma unroll
    for (int k = 0; k < 9; ++k) if (th[k] <= lim) tlm |= (1u << k);
    float q[9];
    #pragma unroll
    for (int k = 0; k < 9; ++k) q[k] = __builtin_amdgcn_exp2f(-th[k] * S);
    unsigned long long mask = __ballot(tlm != 0u);   // this wave's active cin

    const int lr = lane >> 3;                   // 0..7
    const int lc = (lane & 7) * 4;              // 0..28
    const int r   = 8 * w + lr;                 // own output/input row
    const int rm1 = (r - 1 < 0)  ? 0  : r - 1;  // clamped load rows
    const int rp1 = (r + 1 > 31) ? 31 : r + 1;
    const bool okA = (r - 1) >= 0;              // row above exists?
    const bool okC = (r + 1) <= 31;             // row below exists?
    const bool isL = (lane & 7) == 0;           // left image edge group
    const bool isR = (lane & 7) == 7;           // right image edge group
    const int  lcl = isL ? 0 : lc - 1;          // clamped edge-scalar cols
    const int  lcr = isR ? 31 : lc + 4;

    float acc0 = 0.f, acc1 = 0.f, acc2 = 0.f, acc3 = 0.f;

    auto pop = [&]() -> int {
        if (!mask) return -1;
        const int c = (int)__builtin_ctzll(mask); mask &= mask - 1; return c;
    };
    // load only live rows (liveness via wave-uniform shuffle of tlm)
    auto issue = [&](int cin, float4& A, float4& B, float4& C,
                     float2& eA, float2& eB, float2& eC) {
        const unsigned tc = (unsigned)__shfl((int)tlm, cin);
        const float* src = vbase + cin * PIX;
        if (tc & 7u) {
            const float* ra = src + rm1 * HW;
            A = *reinterpret_cast<const float4*>(ra + lc);
            eA.x = ra[lcl]; eA.y = ra[lcr];
        }
        if (tc & 56u) {
            const float* rb = src + r * HW;
            B = *reinterpret_cast<const float4*>(rb + lc);
            eB.x = rb[lcl]; eB.y = rb[lcr];
        }
        if (tc & 448u) {
            const float* rc = src + rp1 * HW;
            C = *reinterpret_cast<const float4*>(rc + lc);
            eC.x = rc[lcl]; eC.y = rc[lcr];
        }
    };
    // row -> 6 exp'd values; pad (v=0 -> e=1) selected BEFORE exp2
    auto rowv = [&](const float4& x, const float2& e, bool ok, float* vals) {
        vals[0] = __builtin_amdgcn_exp2f(((ok && !isL) ? e.x : 0.f) * S);
        vals[1] = __builtin_amdgcn_exp2f((ok ? x.x : 0.f) * S);
        vals[2] = __builtin_amdgcn_exp2f((ok ? x.y : 0.f) * S);
        vals[3] = __builtin_amdgcn_exp2f((ok ? x.z : 0.f) * S);
        vals[4] = __builtin_amdgcn_exp2f((ok ? x.w : 0.f) * S);
        vals[5] = __builtin_amdgcn_exp2f(((ok && !isR) ? e.y : 0.f) * S);
    };
    auto compute = [&](int cin, const float4& A, const float4& B, const float4& C,
                       const float2& eA, const float2& eB, const float2& eC) {
        const unsigned tc = (unsigned)__shfl((int)tlm, cin);
        float qc[9];
        #pragma unroll
        for (int k = 0; k < 9; ++k) qc[k] = __shfl(q[k], cin);
        #pragma unroll
        for (int i = 0; i < 3; ++i) {
            if (!((tc >> (3 * i)) & 7u)) continue;        // tap-row dead
            float vals[6];
            if      (i == 0) rowv(A, eA, okA, vals);
            else if (i == 1) rowv(B, eB, true, vals);
            else             rowv(C, eC, okC, vals);
            #pragma unroll
            for (int j = 0; j < 3; ++j) {
                if (!((tc >> (3 * i + j)) & 1u)) continue; // tap dead
                const float qa = qc[3 * i + j];
                const float qb = qa * KF;
                #pragma unroll
                for (int k = 0; k < 4; ++k) {
                    const float x1 = __builtin_fmaf(vals[k + j], qa, 1.0f);
                    const float x2 = __builtin_fmaf(vals[k + j], qb, 1.0f);
                    const float l1 = __builtin_amdgcn_logf(x1);   // log2
                    const float l2 = __builtin_amdgcn_logf(x2);
                    const float su = l1 + l2, di = l1 - l2;       // l1^2-l2^2
                    if      (k == 0) acc0 = __builtin_fmaf(su, di, acc0);
                    else if (k == 1) acc1 = __builtin_fmaf(su, di, acc1);
                    else if (k == 2) acc2 = __builtin_fmaf(su, di, acc2);
                    else             acc3 = __builtin_fmaf(su, di, acc3);
                }
            }
        }
    };

    // depth-2 pipeline, ping-pong register sets A/B (loads issued 2 planes ahead)
    {
        float4 aA = make_float4(0.f,0.f,0.f,0.f), bA = aA, cA = aA;
        float4 aB = aA, bB = aA, cB = aA;
        float2 eaA = make_float2(0.f,0.f), ebA = eaA, ecA = eaA;
        float2 eaB = eaA, ebB = eaA, ecB = eaA;
        int q0 = pop();
        if (q0 >= 0) {
            issue(q0, aA, bA, cA, eaA, ebA, ecA);
            int q1 = pop();
            if (q1 >= 0) issue(q1, aB, bB, cB, eaB, ebB, ecB);
            for (;;) {
                // EVEN: current plane q0 in set A; 2-ahead issued into dead A regs
                {
                    const float4 xa = aA, xb = bA, xc = cA;
                    const float2 ya = eaA, yb = ebA, yc = ecA;
                    int q2 = (q1 >= 0) ? pop() : -1;
                    if (q2 >= 0) issue(q2, aA, bA, cA, eaA, ebA, ecA);
                    compute(q0, xa, xb, xc, ya, yb, yc);
                    if (q1 < 0) break;
                    q0 = q2;
                }
                // ODD: current plane q1 in set B
                {
                    const float4 xa = aB, xb = bB, xc = cB;
                    const float2 ya = eaB, yb = ebB, yc = ecB;
                    int q3 = (q0 >= 0) ? pop() : -1;
                    if (q3 >= 0) issue(q3, aB, bB, cB, eaB, ebB, ecB);
                    compute(q1, xa, xb, xc, ya, yb, yc);
                    if (q0 < 0) break;
                    q1 = q3;
                }
            }
        }
    }

    // wave-direct store: window px (lr, lc..lc+3) = flat w*256 + 4*lane
    float4 o;
    o.x = acc0 * OSC; o.y = acc1 * OSC; o.z = acc2 * OSC; o.w = acc3 * OSC;
    float* obase = Out + (size_t)(b * COUT + co) * PIX + w * 256;
    reinterpret_cast<float4*>(obase)[lane] = o;
}

extern "C" void kernel_launch(void* const* d_in, const int* in_sizes, int n_in,
                              void* d_out, int out_size, void* d_ws, size_t ws_size,
                              hipStream_t stream) {
    (void)in_sizes; (void)n_in; (void)ws_size; (void)out_size;
    const float* V  = (const float*)d_in[0];   // (4,64,32,32)
    const float* Th = (const float*)d_in[1];   // (128,64,3,3)
    float* Out = (float*)d_out;                // (4,128,32,32)
    float* wg  = (float*)d_ws;                 // 4*64*4 floats = 4 KB
    ekv_rowmax<<<dim3(4 * CIN), dim3(256), 0, stream>>>(V, wg);
    ekv_main<<<dim3(4 * COUT), dim3(256), 0, stream>>>(V, Th, wg, Out);
}